// Round 6
// baseline (81.923 us; speedup 1.0000x reference)
//
#include <hip/hip_runtime.h>
#include <stdint.h>

#define CIN   64
#define COUT  64
#define HH    112
#define WW    112
#define NEXP  4
#define HW    (HH * WW)

typedef short bf16x8 __attribute__((ext_vector_type(8)));
typedef float f32x16 __attribute__((ext_vector_type(16)));

__device__ inline uint16_t f2bf(float f) {
    uint32_t u = __builtin_bit_cast(uint32_t, f);
    return (uint16_t)((u + 0x7FFFu + ((u >> 16) & 1u)) >> 16);
}

// ---------------------------------------------------------------------------
// Fold gates into per-sample weights (bf16) and biases (f32).
// Weff layout: [n][g=72][co=64][j=8] where g = ((phase*9+khw)*2+kq)*2+par,
// k-global ci = phase*32 + (kq*2+par)*8 + j.  co second-fastest => the MFMA
// A-fragment load (lane&31 = co, 16B/lane) reads 512 contiguous bytes.
// ---------------------------------------------------------------------------
__global__ __launch_bounds__(256)
void fold_wb(const float* __restrict__ W, const float* __restrict__ bias,
             const float* __restrict__ mask,
             uint16_t* __restrict__ Weff, float* __restrict__ Beff, int B) {
    int idx = blockIdx.x * 256 + threadIdx.x;
    if (idx >= B * 72 * 512) return;
    int j   = idx & 7;
    int co  = (idx >> 3) & 63;
    int g   = (idx >> 9) % 72;
    int n   = idx / (512 * 72);
    int par   = g & 1;
    int kq    = (g >> 1) & 1;
    int khw   = (g >> 2) % 9;
    int phase = (g >> 2) / 9;
    int ci = phase * 32 + (kq * 2 + par) * 8 + j;
    float acc = 0.f;
#pragma unroll
    for (int e = 0; e < NEXP; ++e)
        acc = fmaf(mask[n * NEXP + e],
                   W[((size_t)(e * COUT + co) * CIN + ci) * 9 + khw], acc);
    Weff[idx] = f2bf(acc);
    if (g == 0 && j == 0) {
        float ba = 0.f;
#pragma unroll
        for (int e = 0; e < NEXP; ++e)
            ba = fmaf(mask[n * NEXP + e], bias[e * COUT + co], ba);
        Beff[n * COUT + co] = ba;
    }
}

// ---------------------------------------------------------------------------
// Staging helpers.  Unit u in [0,1296): s = u&3 (16B LDS granule slot),
// pix = u>>2 (18x18 halo pixel).  Swizzle: slot s holds ci-octet s^((pix>>1)&3).
// ---------------------------------------------------------------------------
__device__ inline void load_unit(const float* __restrict__ xph, int u,
                                 int h0, int w0, float r[8]) {
    int s   = u & 3;
    int pix = u >> 2;
    int dh = pix / 18, dw = pix - dh * 18;
    int h = h0 + dh - 1, w = w0 + dw - 1;
    int cg = s ^ ((pix >> 1) & 3);
    if ((unsigned)h < (unsigned)HH && (unsigned)w < (unsigned)WW) {
        const float* xp = xph + ((size_t)(cg * 8) * HH + h) * WW + w;
#pragma unroll
        for (int j = 0; j < 8; ++j) r[j] = xp[(size_t)j * HW];
    } else {
#pragma unroll
        for (int j = 0; j < 8; ++j) r[j] = 0.f;
    }
}

__device__ inline void pack_write(uint16_t* __restrict__ buf, int u,
                                  const float r[8]) {
    int s   = u & 3;
    int pix = u >> 2;
    union { uint16_t e[8]; uint4 v; } pk;
#pragma unroll
    for (int j = 0; j < 8; ++j) pk.e[j] = f2bf(r[j]);
    *(uint4*)(&buf[pix * 32 + s * 8]) = pk.v;
}

__device__ inline void compute_phase(const uint16_t* __restrict__ buf,
                                     const uint16_t* __restrict__ wp,
                                     int rowb, int colb, int par,
                                     f32x16& acc00, f32x16& acc01,
                                     f32x16& acc10, f32x16& acc11) {
#pragma unroll 3
    for (int khw = 0; khw < 9; ++khw) {
        const int dh = khw / 3;
        const int dw = khw - dh * 3;
        const int pb0 = (rowb + dh) * 18 + (colb + dw);
        const int pb1 = pb0 + 36;              // nf=1: +2 pixel rows
        const int f0 = (pb0 >> 1) & 3, f1 = (pb1 >> 1) & 3;
        const uint16_t* lp0 = &buf[pb0 * 32];
        const uint16_t* lp1 = &buf[pb1 * 32];
#pragma unroll
        for (int kq = 0; kq < 2; ++kq) {
            const int cgA = kq * 2 + par;
            bf16x8 b0 = *(const bf16x8*)(lp0 + ((cgA ^ f0) << 3));
            bf16x8 b1 = *(const bf16x8*)(lp1 + ((cgA ^ f1) << 3));
            const uint16_t* wk = wp + (size_t)((khw * 2 + kq) * 2) * 512;
            bf16x8 a0 = *(const bf16x8*)(wk);
            bf16x8 a1 = *(const bf16x8*)(wk + 256);   // co+32
            acc00 = __builtin_amdgcn_mfma_f32_32x32x16_bf16(a0, b0, acc00, 0, 0, 0);
            acc01 = __builtin_amdgcn_mfma_f32_32x32x16_bf16(a0, b1, acc01, 0, 0, 0);
            acc10 = __builtin_amdgcn_mfma_f32_32x32x16_bf16(a1, b0, acc10, 0, 0, 0);
            acc11 = __builtin_amdgcn_mfma_f32_32x32x16_bf16(a1, b1, acc11, 0, 0, 0);
        }
    }
}

// ---------------------------------------------------------------------------
// Fused conv, T14 phase pipeline:
//   stage(buf0,ph0); barrier;
//   issue ph1 global loads -> regs;            (hidden under ph0 compute)
//   compute(ph0); pack+write(buf1); barrier;
//   compute(ph1)
// LDS: 2 x [324 pix][32 ci] bf16 = 41472 B -> 3 blocks/CU (matches VGPR cap).
// NOTE: min-waves must stay <=3: 64 acc VGPRs + ~48 prefetch regs; a lower
// cap spills accs to scratch (round-4: 1.77 GB scratch traffic, 7x slower).
// ---------------------------------------------------------------------------
__global__ __launch_bounds__(256, 3)
void conv_fused(const float* __restrict__ x, const uint16_t* __restrict__ Weff,
                const float* __restrict__ Beff, float* __restrict__ out,
                int nwg) {
    __shared__ uint16_t ldsx[2][324 * 32];   // 2 x 20736 B

    // T1 XCD swizzle (nwg = 1568, %8 == 0): contiguous chunk per XCD so a
    // sample's 49 blocks share one L2's copy of its 72KB weights.
    int bid = blockIdx.x;
    if ((nwg & 7) == 0)
        bid = (bid & 7) * (nwg >> 3) + (bid >> 3);

    const int tid  = threadIdx.x;
    const int lane = tid & 63;
    const int wid  = tid >> 6;
    const int tileIdx = bid % 49;
    const int n  = bid / 49;
    const int th = tileIdx / 7, tw = tileIdx % 7;
    const int h0 = th * 16, w0 = tw * 16;

    const int rowb = wid * 4 + ((lane & 31) >> 4); // pixel row (nf=0)
    const int colb = lane & 15;                    // pixel col
    const int par  = lane >> 5;                    // k-octet parity

    const uint16_t* wbase = Weff + (size_t)n * 36864
                          + (size_t)par * 512 + (size_t)(lane & 31) * 8;
    const float* xn = x + (size_t)n * CIN * HW;

    f32x16 acc00 = {}, acc01 = {}, acc10 = {}, acc11 = {};

    // ---- stage phase 0 (ci 0..31) into buf0: load+pack+write immediate
    for (int u = tid; u < 1296; u += 256) {
        float r[8];
        load_unit(xn, u, h0, w0, r);
        pack_write(ldsx[0], u, r);
    }
    __syncthreads();

    // ---- issue phase-1 (ci 32..63) loads now; they retire under compute-0
    const float* xph1 = xn + (size_t)32 * HW;
    float pre[5][8];
    float pret[8];
    const bool tail = (tid < 16);
#pragma unroll
    for (int i = 0; i < 5; ++i)
        load_unit(xph1, i * 256 + tid, h0, w0, pre[i]);
    if (tail) load_unit(xph1, 1280 + tid, h0, w0, pret);

    // ---- compute phase 0
    compute_phase(ldsx[0], wbase, rowb, colb, par, acc00, acc01, acc10, acc11);

    // ---- drain prefetch into buf1 (no WAR hazard: different buffer)
#pragma unroll
    for (int i = 0; i < 5; ++i)
        pack_write(ldsx[1], i * 256 + tid, pre[i]);
    if (tail) pack_write(ldsx[1], 1280 + tid, pret);
    __syncthreads();

    // ---- compute phase 1
    compute_phase(ldsx[1], wbase + (size_t)36 * 512, rowb, colb, par,
                  acc00, acc01, acc10, acc11);

    // ---- epilogue: C/D layout col=lane&31 (pixel), row=(r&3)+8*(r>>2)+4*par
    const float* bptr = Beff + n * 64;
    const int row0 = h0 + rowb;
    const int col  = w0 + colb;
#pragma unroll
    for (int r = 0; r < 16; ++r) {
        const int co = (r & 3) + 8 * (r >> 2) + 4 * par;
        const float bia0 = bptr[co];
        const float bia1 = bptr[co + 32];
        size_t o00 = ((size_t)(n * COUT + co) * HH + row0) * WW + col;
        __builtin_nontemporal_store(acc00[r] + bia0, &out[o00]);
        __builtin_nontemporal_store(acc01[r] + bia0, &out[o00 + 2 * WW]);
        size_t o10 = o00 + (size_t)32 * HW;
        __builtin_nontemporal_store(acc10[r] + bia1, &out[o10]);
        __builtin_nontemporal_store(acc11[r] + bia1, &out[o10 + 2 * WW]);
    }
}

// ---------------------------------------------------------------------------
// Fallback (round-1 path): per-sample folded weights, fp32 vector conv.
// ---------------------------------------------------------------------------
#define COB   8
#define PIX_PER_BLK 256
#define NTILE (HW / PIX_PER_BLK)

__global__ void fold_weights(const float* __restrict__ W,
                             const float* __restrict__ mask,
                             float* __restrict__ Weff, int B) {
    int idx = blockIdx.x * blockDim.x + threadIdx.x;
    int total = B * CIN * 9 * COUT;
    if (idx >= total) return;
    int co = idx % COUT;
    int t  = idx / COUT;
    int k  = t % 9;
    t /= 9;
    int ci = t % CIN;
    int n  = t / CIN;
    float acc = 0.f;
#pragma unroll
    for (int e = 0; e < NEXP; ++e)
        acc = fmaf(mask[n * NEXP + e],
                   W[(((size_t)(e * COUT + co) * CIN + ci) * 9) + k], acc);
    Weff[idx] = acc;
}

__global__ __launch_bounds__(PIX_PER_BLK, 4)
void conv_gated(const float* __restrict__ x,
                const float* __restrict__ mask,
                const float* __restrict__ bias,
                const float* __restrict__ Weff,
                float* __restrict__ out) {
    const int tile = blockIdx.x % NTILE;
    const int cob  = (blockIdx.x / NTILE) % (COUT / COB);
    const int n    = blockIdx.x / (NTILE * (COUT / COB));
    const int p = tile * PIX_PER_BLK + threadIdx.x;
    const int h = p / WW;
    const int w = p % WW;
    const int co0 = cob * COB;

    float acc[COB];
#pragma unroll
    for (int j = 0; j < COB; ++j) {
        float a = 0.f;
#pragma unroll
        for (int e = 0; e < NEXP; ++e)
            a = fmaf(mask[n * NEXP + e], bias[e * COUT + co0 + j], a);
        acc[j] = a;
    }

    const float* xb = x + (((size_t)n * CIN) * HH + h) * WW + w;
    const float* wb = Weff + ((size_t)n * CIN) * 9 * COUT + co0;
    const bool rok0 = (h > 0), rok2 = (h < HH - 1);
    const bool cok0 = (w > 0), cok2 = (w < WW - 1);

    for (int ci = 0; ci < CIN; ++ci) {
        const float* xc = xb + (size_t)ci * HW;
        const float* wc = wb + (size_t)ci * 9 * COUT;
#pragma unroll
        for (int kh = 0; kh < 3; ++kh) {
            const bool rok = (kh == 0) ? rok0 : ((kh == 2) ? rok2 : true);
#pragma unroll
            for (int kw = 0; kw < 3; ++kw) {
                const bool cok = (kw == 0) ? cok0 : ((kw == 2) ? cok2 : true);
                float xv = (rok && cok) ? xc[(kh - 1) * WW + (kw - 1)] : 0.f;
                const float4* wk = (const float4*)(wc + (kh * 3 + kw) * COUT);
                float4 wa = wk[0], wb4 = wk[1];
                acc[0] = fmaf(xv, wa.x, acc[0]);
                acc[1] = fmaf(xv, wa.y, acc[1]);
                acc[2] = fmaf(xv, wa.z, acc[2]);
                acc[3] = fmaf(xv, wa.w, acc[3]);
                acc[4] = fmaf(xv, wb4.x, acc[4]);
                acc[5] = fmaf(xv, wb4.y, acc[5]);
                acc[6] = fmaf(xv, wb4.z, acc[6]);
                acc[7] = fmaf(xv, wb4.w, acc[7]);
            }
        }
    }
    float* ob = out + (((size_t)(n * COUT + co0)) * HH + h) * WW + w;
#pragma unroll
    for (int j = 0; j < COB; ++j)
        ob[(size_t)j * HW] = acc[j];
}

// ---------------------------------------------------------------------------
extern "C" void kernel_launch(void* const* d_in, const int* in_sizes, int n_in,
                              void* d_out, int out_size, void* d_ws, size_t ws_size,
                              hipStream_t stream) {
    const float* x    = (const float*)d_in[0];
    const float* mask = (const float*)d_in[1];
    const float* W    = (const float*)d_in[2];
    const float* b    = (const float*)d_in[3];
    float* out = (float*)d_out;

    const int B = in_sizes[0] / (CIN * HW);
    const size_t weffB = (size_t)B * 36864 * 2;
    const size_t beffB = (size_t)B * COUT * 4;
    const size_t need  = weffB + beffB;

    if (ws_size >= need) {
        uint16_t* Weff = (uint16_t*)d_ws;
        float*    Beff = (float*)((char*)d_ws + weffB);
        int foldBlocks = (B * 72 * 512 + 255) / 256;
        fold_wb<<<foldBlocks, 256, 0, stream>>>(W, b, mask, Weff, Beff, B);
        const int nwg = B * 49;
        conv_fused<<<nwg, 256, 0, stream>>>(x, Weff, Beff, out, nwg);
    } else {
        float* Weff = (float*)d_ws;
        const size_t weff_elems = (size_t)B * CIN * 9 * COUT;
        int foldBlocks = (int)((weff_elems + 255) / 256);
        fold_weights<<<foldBlocks, 256, 0, stream>>>(W, mask, Weff, B);
        conv_gated<<<B * (COUT / COB) * NTILE, PIX_PER_BLK, 0, stream>>>(
            x, mask, b, Weff, out);
    }
}